// Round 1
// baseline (335.428 us; speedup 1.0000x reference)
//
#include <hip/hip_runtime.h>

// Problem: B=16, C=128, K=128, D=256. Inputs f32, outputs FLOAT32.
// d_out (float): out0 (B,C,D) @ 0, out1 (B,C,K,D) @ 524288, out2 (B,C,K) @ 67633152.

#define NB 16
#define NC 128
#define NK 128
#define ND 256

typedef float f4v __attribute__((ext_vector_type(4)));

// ---------------- Kernel 1: dual SGEMM  Y[m,d] = sum_j A[m,j]*W[d,j] ----------------
// M = 4096 (rows 0..2047 = q with W0, rows 2048..4095 = kc with W1), K=256, N=256.
// 64x64 tile per block, 256 threads, 4x4 microtile, K-chunk 16.
__global__ __launch_bounds__(256) void k_gemm(const float* __restrict__ q,
                                              const float* __restrict__ kc,
                                              const float* __restrict__ W0,
                                              const float* __restrict__ W1,
                                              float* __restrict__ Y) {
    __shared__ float As[16][64];
    __shared__ float Bs[16][64];
    const int m0 = blockIdx.x * 64;
    const int d0 = blockIdx.y * 64;
    const int t  = threadIdx.x;
    const float* A = (m0 < 2048) ? (q + (size_t)m0 * ND) : (kc + (size_t)(m0 - 2048) * ND);
    const float* W = (m0 < 2048) ? W0 : W1;
    const int ml = t >> 2;          // 0..63 (row within tile for loads)
    const int jl = (t & 3) * 4;     // 0,4,8,12 (k within chunk)
    const int ty = t >> 4;          // 0..15 -> m sub-tile
    const int tx = t & 15;          // 0..15 -> n sub-tile

    float acc[4][4] = {};
    for (int j0 = 0; j0 < 256; j0 += 16) {
        float4 a = *(const float4*)(A + ml * ND + j0 + jl);
        float4 b = *(const float4*)(W + (d0 + ml) * ND + j0 + jl);
        As[jl + 0][ml] = a.x; As[jl + 1][ml] = a.y; As[jl + 2][ml] = a.z; As[jl + 3][ml] = a.w;
        Bs[jl + 0][ml] = b.x; Bs[jl + 1][ml] = b.y; Bs[jl + 2][ml] = b.z; Bs[jl + 3][ml] = b.w;
        __syncthreads();
#pragma unroll
        for (int jj = 0; jj < 16; ++jj) {
            float4 av = *(const float4*)&As[jj][ty * 4];
            float4 bv = *(const float4*)&Bs[jj][tx * 4];
            acc[0][0] += av.x * bv.x; acc[0][1] += av.x * bv.y; acc[0][2] += av.x * bv.z; acc[0][3] += av.x * bv.w;
            acc[1][0] += av.y * bv.x; acc[1][1] += av.y * bv.y; acc[1][2] += av.y * bv.z; acc[1][3] += av.y * bv.w;
            acc[2][0] += av.z * bv.x; acc[2][1] += av.z * bv.y; acc[2][2] += av.z * bv.z; acc[2][3] += av.z * bv.w;
            acc[3][0] += av.w * bv.x; acc[3][1] += av.w * bv.y; acc[3][2] += av.w * bv.z; acc[3][3] += av.w * bv.w;
        }
        __syncthreads();
    }
#pragma unroll
    for (int i = 0; i < 4; ++i) {
        float4 o = make_float4(acc[i][0], acc[i][1], acc[i][2], acc[i][3]);
        *(float4*)(Y + (size_t)(m0 + ty * 4 + i) * ND + d0 + tx * 4) = o;
    }
}

// ---------------- Kernel 2: BN stats per channel (256 channels: 0..127 bn0, 128..255 bn1) ----
__global__ __launch_bounds__(256) void k_stats(const float* __restrict__ Y,
                                               const float* __restrict__ g0, const float* __restrict__ b0,
                                               const float* __restrict__ g1, const float* __restrict__ b1,
                                               float* __restrict__ sc, float* __restrict__ sh) {
    const int ch = blockIdx.x;
    const int t  = threadIdx.x;
    const int rbase = (ch < 128) ? ch : (2048 + (ch - 128));
    float s = 0.f, s2 = 0.f;
#pragma unroll
    for (int b = 0; b < NB; ++b) {
        float v = Y[(size_t)(rbase + b * 128) * ND + t];
        s += v; s2 += v * v;
    }
#pragma unroll
    for (int off = 32; off > 0; off >>= 1) {
        s  += __shfl_down(s,  off, 64);
        s2 += __shfl_down(s2, off, 64);
    }
    __shared__ float r1[4], r2[4];
    const int w = t >> 6;
    if ((t & 63) == 0) { r1[w] = s; r2[w] = s2; }
    __syncthreads();
    if (t == 0) {
        s  = r1[0] + r1[1] + r1[2] + r1[3];
        s2 = r2[0] + r2[1] + r2[2] + r2[3];
        float mean = s * (1.f / 4096.f);
        float var  = s2 * (1.f / 4096.f) - mean * mean;   // biased, matches torch/jnp
        float rstd = rsqrtf(var + 1e-5f);
        float g  = (ch < 128) ? g0[ch] : g1[ch - 128];
        float be = (ch < 128) ? b0[ch] : b1[ch - 128];
        sc[ch] = g * rstd;
        sh[ch] = be - mean * g * rstd;
    }
}

// ---------------- Kernel 3: in-place sigmoid(BN(Y)) ----------------
__global__ __launch_bounds__(256) void k_apply(float* __restrict__ Y,
                                               const float* __restrict__ sc, const float* __restrict__ sh) {
    const int m = blockIdx.x;          // 0..4095
    const int t = threadIdx.x;
    const size_t idx = (size_t)m * ND + t;
    float x = Y[idx];
    const int ch = (m < 2048) ? (m & 127) : (128 + (m & 127));
    float g = x * sc[ch] + sh[ch];
    Y[idx] = 1.f / (1.f + __expf(-g));
}

// ---------------- Kernel 4: out2[b,c,k] = (1/256) * sum_d s0sig[b,c,d]*s1sig[b,k,d] --------
// Per-b GEMM, 64x64 tile over (c,k), K-dim = 256. grid (2,2,16).
__global__ __launch_bounds__(256) void k_out2(const float* __restrict__ Y,
                                              float* __restrict__ out2) {
    __shared__ float As[16][64];
    __shared__ float Bs[16][64];
    const int b  = blockIdx.z;
    const int c0 = blockIdx.x * 64;
    const int k0 = blockIdx.y * 64;
    const int t  = threadIdx.x;
    const float* A = Y + (size_t)(b * 128 + c0) * ND;           // s0 sigmoid rows (unmasked)
    const float* W = Y + (size_t)(2048 + b * 128 + k0) * ND;    // s1 sigmoid rows (unmasked)
    const int ml = t >> 2;
    const int jl = (t & 3) * 4;
    const int ty = t >> 4;
    const int tx = t & 15;

    float acc[4][4] = {};
    for (int j0 = 0; j0 < 256; j0 += 16) {
        float4 a = *(const float4*)(A + ml * ND + j0 + jl);
        float4 bv_ = *(const float4*)(W + ml * ND + j0 + jl);
        As[jl + 0][ml] = a.x; As[jl + 1][ml] = a.y; As[jl + 2][ml] = a.z; As[jl + 3][ml] = a.w;
        Bs[jl + 0][ml] = bv_.x; Bs[jl + 1][ml] = bv_.y; Bs[jl + 2][ml] = bv_.z; Bs[jl + 3][ml] = bv_.w;
        __syncthreads();
#pragma unroll
        for (int jj = 0; jj < 16; ++jj) {
            float4 av = *(const float4*)&As[jj][ty * 4];
            float4 bv = *(const float4*)&Bs[jj][tx * 4];
            acc[0][0] += av.x * bv.x; acc[0][1] += av.x * bv.y; acc[0][2] += av.x * bv.z; acc[0][3] += av.x * bv.w;
            acc[1][0] += av.y * bv.x; acc[1][1] += av.y * bv.y; acc[1][2] += av.y * bv.z; acc[1][3] += av.y * bv.w;
            acc[2][0] += av.z * bv.x; acc[2][1] += av.z * bv.y; acc[2][2] += av.z * bv.z; acc[2][3] += av.z * bv.w;
            acc[3][0] += av.w * bv.x; acc[3][1] += av.w * bv.y; acc[3][2] += av.w * bv.z; acc[3][3] += av.w * bv.w;
        }
        __syncthreads();
    }
    const float scale = 1.f / 256.f;
#pragma unroll
    for (int i = 0; i < 4; ++i) {
        float4 o = make_float4(acc[i][0] * scale, acc[i][1] * scale, acc[i][2] * scale, acc[i][3] * scale);
        *(float4*)(out2 + ((size_t)(b * 128 + c0 + ty * 4 + i)) * 128 + k0 + tx * 4) = o;
    }
}

// ---------------- Kernel 5: in-place u = kmask * kc * s1sig over s1 rows of Y ----------------
__global__ __launch_bounds__(256) void k_u(float* __restrict__ Y,
                                           const float* __restrict__ kc,
                                           const int* __restrict__ kmask) {
    const int r = blockIdx.x;          // 0..2047 = b*128 + k
    const int t = threadIdx.x;
    const size_t idx = (size_t)(2048 + r) * ND + t;
    const float km = (float)kmask[r];
    Y[idx] = km * kc[(size_t)r * ND + t] * Y[idx];
}

// ---------------- Kernel 6: t[b,d] = sum_k u[b,k,d] ----------------
__global__ __launch_bounds__(256) void k_t(const float* __restrict__ Y,
                                           float* __restrict__ tvec) {
    const int b = blockIdx.x;          // 0..15
    const int t = threadIdx.x;         // d
    const float* u = Y + (size_t)(2048 + b * 128) * ND;
    float s0 = 0.f, s1 = 0.f, s2 = 0.f, s3 = 0.f;
#pragma unroll 8
    for (int k = 0; k < 128; k += 4) {
        s0 += u[(size_t)(k + 0) * ND + t];
        s1 += u[(size_t)(k + 1) * ND + t];
        s2 += u[(size_t)(k + 2) * ND + t];
        s3 += u[(size_t)(k + 3) * ND + t];
    }
    tvec[b * ND + t] = (s0 + s1) + (s2 + s3);
}

// ---------------- Kernel 7: streaming outer-product out1 + out0 ----------------
// One block per (b,c). 256 threads: f = t&63 covers d via float4, g = t>>6 covers k phase.
__global__ __launch_bounds__(256) void k_big2(const float* __restrict__ Y,   // s0sig rows [0,2048); u rows [2048,4096)
                                              const float* __restrict__ tvec,
                                              const int* __restrict__ cmask,
                                              const int* __restrict__ klen,
                                              float* __restrict__ out0,
                                              float* __restrict__ out1) {
    const int bc = blockIdx.x;     // b*128 + c
    const int b  = bc >> 7;
    const int t  = threadIdx.x;
    const int f  = t & 63;
    const int g  = t >> 6;

    float4 s0v = *(const float4*)(Y + (size_t)bc * ND + f * 4);
    const bool cm = cmask[bc] != 0;
    float4 v0 = cm ? s0v : make_float4(0.f, 0.f, 0.f, 0.f);

    const float* up = Y + (size_t)(2048 + b * 128 + g) * ND + f * 4;
    float*       op = out1 + (size_t)bc * 128 * ND + (size_t)g * ND + f * 4;

#pragma unroll 4
    for (int k0 = 0; k0 < 32; ++k0) {
        float4 uv = *(const float4*)up;
        float4 o = make_float4(v0.x * uv.x, v0.y * uv.y, v0.z * uv.z, v0.w * uv.w);
        __builtin_nontemporal_store(*(const f4v*)&o, (f4v*)op);
        up += 4 * ND;
        op += 4 * ND;
    }

    if (g == 0) {
        float4 tv = *(const float4*)(tvec + b * ND + f * 4);
        const float inv = 1.f / (float)klen[b];
        float4 o0 = make_float4(tanhf(v0.x * tv.x * inv), tanhf(v0.y * tv.y * inv),
                                tanhf(v0.z * tv.z * inv), tanhf(v0.w * tv.w * inv));
        *(float4*)(out0 + (size_t)bc * ND + f * 4) = o0;
    }
}

extern "C" void kernel_launch(void* const* d_in, const int* in_sizes, int n_in,
                              void* d_out, int out_size, void* d_ws, size_t ws_size,
                              hipStream_t stream) {
    const float* q     = (const float*)d_in[0];
    const float* kc    = (const float*)d_in[1];
    const float* W0    = (const float*)d_in[2];
    const float* W1    = (const float*)d_in[3];
    const float* g0    = (const float*)d_in[4];
    const float* b0    = (const float*)d_in[5];
    const float* g1    = (const float*)d_in[6];
    const float* b1    = (const float*)d_in[7];
    const int*   cmask = (const int*)d_in[8];
    const int*   kmask = (const int*)d_in[9];
    const int*   klen  = (const int*)d_in[10];

    float* ws = (float*)d_ws;
    float* Y  = ws;                 // 4096*256 = 1048576 f32
    float* sc = ws + 1048576;       // 256
    float* sh = ws + 1048832;       // 256
    float* tv = ws + 1049088;       // 16*256 = 4096

    float* o    = (float*)d_out;
    float* out0 = o;                 // 16*128*256      = 524288
    float* out1 = o + 524288;        // 16*128*128*256  = 67108864
    float* out2 = o + 67633152;      // 16*128*128      = 262144

    k_gemm <<<dim3(64, 4),    256, 0, stream>>>(q, kc, W0, W1, Y);
    k_stats<<<256,            256, 0, stream>>>(Y, g0, b0, g1, b1, sc, sh);
    k_apply<<<4096,           256, 0, stream>>>(Y, sc, sh);
    k_out2 <<<dim3(2, 2, 16), 256, 0, stream>>>(Y, out2);          // consumes unmasked s1sig
    k_u    <<<2048,           256, 0, stream>>>(Y, kc, kmask);     // overwrites s1 rows with u
    k_t    <<<16,             256, 0, stream>>>(Y, tv);
    k_big2 <<<2048,           256, 0, stream>>>(Y, tv, cmask, klen, out0, out1);
}

// Round 2
// 324.407 us; speedup vs baseline: 1.0340x; 1.0340x over previous
//
#include <hip/hip_runtime.h>

// Problem: B=16, C=128, K=128, D=256. Inputs f32, outputs FLOAT32.
// d_out (float): out0 (B,C,D) @ 0, out1 (B,C,K,D) @ 524288, out2 (B,C,K) @ 67633152.

#define NB 16
#define NC 128
#define NK 128
#define ND 256

// ---------------- Kernel 1: dual SGEMM  Y[m,d] = sum_j A[m,j]*W[d,j]  (+ zero tvec) --------
// M = 4096 (rows 0..2047 = q with W0, rows 2048..4095 = kc with W1), K=256, N=256.
// 64x64 tile per block, 256 threads, 4x4 microtile, K-chunk 16.
__global__ __launch_bounds__(256) void k_gemm(const float* __restrict__ q,
                                              const float* __restrict__ kc,
                                              const float* __restrict__ W0,
                                              const float* __restrict__ W1,
                                              float* __restrict__ Y,
                                              float* __restrict__ tvec) {
    if (blockIdx.x == 0 && blockIdx.y == 0) {
        for (int i = threadIdx.x; i < NB * ND; i += 256) tvec[i] = 0.f;
    }
    __shared__ float As[16][64];
    __shared__ float Bs[16][64];
    const int m0 = blockIdx.x * 64;
    const int d0 = blockIdx.y * 64;
    const int t  = threadIdx.x;
    const float* A = (m0 < 2048) ? (q + (size_t)m0 * ND) : (kc + (size_t)(m0 - 2048) * ND);
    const float* W = (m0 < 2048) ? W0 : W1;
    const int ml = t >> 2;          // 0..63 (row within tile for loads)
    const int jl = (t & 3) * 4;     // 0,4,8,12 (k within chunk)
    const int ty = t >> 4;          // 0..15 -> m sub-tile
    const int tx = t & 15;          // 0..15 -> n sub-tile

    float acc[4][4] = {};
    for (int j0 = 0; j0 < 256; j0 += 16) {
        float4 a = *(const float4*)(A + ml * ND + j0 + jl);
        float4 b = *(const float4*)(W + (d0 + ml) * ND + j0 + jl);
        As[jl + 0][ml] = a.x; As[jl + 1][ml] = a.y; As[jl + 2][ml] = a.z; As[jl + 3][ml] = a.w;
        Bs[jl + 0][ml] = b.x; Bs[jl + 1][ml] = b.y; Bs[jl + 2][ml] = b.z; Bs[jl + 3][ml] = b.w;
        __syncthreads();
#pragma unroll
        for (int jj = 0; jj < 16; ++jj) {
            float4 av = *(const float4*)&As[jj][ty * 4];
            float4 bv = *(const float4*)&Bs[jj][tx * 4];
            acc[0][0] += av.x * bv.x; acc[0][1] += av.x * bv.y; acc[0][2] += av.x * bv.z; acc[0][3] += av.x * bv.w;
            acc[1][0] += av.y * bv.x; acc[1][1] += av.y * bv.y; acc[1][2] += av.y * bv.z; acc[1][3] += av.y * bv.w;
            acc[2][0] += av.z * bv.x; acc[2][1] += av.z * bv.y; acc[2][2] += av.z * bv.z; acc[2][3] += av.z * bv.w;
            acc[3][0] += av.w * bv.x; acc[3][1] += av.w * bv.y; acc[3][2] += av.w * bv.z; acc[3][3] += av.w * bv.w;
        }
        __syncthreads();
    }
#pragma unroll
    for (int i = 0; i < 4; ++i) {
        float4 o = make_float4(acc[i][0], acc[i][1], acc[i][2], acc[i][3]);
        *(float4*)(Y + (size_t)(m0 + ty * 4 + i) * ND + d0 + tx * 4) = o;
    }
}

// ---------------- Kernel 2: fused BN-stats + sigmoid-apply (+ tvec accumulation) ------------
// One block per channel (256 channels: 0..127 bn0/s0 rows, 128..255 bn1/s1 rows).
// Thread t = column d. Row values kept in registers between stats and apply.
__global__ __launch_bounds__(256) void k_sau(float* __restrict__ Y,
                                             const float* __restrict__ kc,
                                             const float* __restrict__ g0, const float* __restrict__ b0,
                                             const float* __restrict__ g1, const float* __restrict__ b1,
                                             const int* __restrict__ kmask,
                                             float* __restrict__ tvec) {
    const int ch = blockIdx.x;
    const int t  = threadIdx.x;
    const int rbase = (ch < 128) ? ch : (2048 + (ch - 128));
    float v[NB];
    float s = 0.f, s2 = 0.f;
#pragma unroll
    for (int b = 0; b < NB; ++b) {
        v[b] = Y[(size_t)(rbase + b * 128) * ND + t];
        s += v[b]; s2 += v[b] * v[b];
    }
#pragma unroll
    for (int off = 32; off > 0; off >>= 1) {
        s  += __shfl_down(s,  off, 64);
        s2 += __shfl_down(s2, off, 64);
    }
    __shared__ float r1[4], r2[4];
    __shared__ float bsc, bsh;
    const int w = t >> 6;
    if ((t & 63) == 0) { r1[w] = s; r2[w] = s2; }
    __syncthreads();
    if (t == 0) {
        s  = r1[0] + r1[1] + r1[2] + r1[3];
        s2 = r2[0] + r2[1] + r2[2] + r2[3];
        float mean = s * (1.f / 4096.f);
        float var  = s2 * (1.f / 4096.f) - mean * mean;   // biased, matches torch/jnp
        float rstd = rsqrtf(var + 1e-5f);
        float g  = (ch < 128) ? g0[ch] : g1[ch - 128];
        float be = (ch < 128) ? b0[ch] : b1[ch - 128];
        bsc = g * rstd;
        bsh = be - mean * g * rstd;
    }
    __syncthreads();
    const float sc = bsc, sh = bsh;
    if (ch < 128) {
#pragma unroll
        for (int b = 0; b < NB; ++b) {
            float sig = 1.f / (1.f + __expf(-(v[b] * sc + sh)));
            Y[(size_t)(rbase + b * 128) * ND + t] = sig;
        }
    } else {
        const int k = ch - 128;
#pragma unroll
        for (int b = 0; b < NB; ++b) {
            float sig = 1.f / (1.f + __expf(-(v[b] * sc + sh)));
            Y[(size_t)(rbase + b * 128) * ND + t] = sig;
            if (kmask[b * 128 + k] != 0) {                   // wave-uniform branch
                float u = kc[(size_t)(b * 128 + k) * ND + t] * sig;
                atomicAdd(&tvec[b * ND + t], u);
            }
        }
    }
}

// ---------------- Kernel 3: fat tail — out2 GEMM + out0 + out1 stream --------------------
// Blocks 0..63: out2[b,c,k] = (1/256) * sum_d s0sig*s1sig   (per-b 64x64 GEMM tiles)
// Blocks 64..319: out0[b,c,d] = tanh(cmask*s0sig*tvec[b,d]/klen[b])
// Blocks 320..2367: out1[b,c,k,d] = cmask*s0sig * kmask*kc*s1sig  (pure store stream)
__global__ __launch_bounds__(256) void k_tail(const float* __restrict__ Y,
                                              const float* __restrict__ kc,
                                              const int* __restrict__ cmask,
                                              const int* __restrict__ kmask,
                                              const int* __restrict__ klen,
                                              const float* __restrict__ tvec,
                                              float* __restrict__ out0,
                                              float* __restrict__ out1,
                                              float* __restrict__ out2) {
    __shared__ float As[16][64];
    __shared__ float Bs[16][64];
    const int bid = blockIdx.x;
    const int t   = threadIdx.x;

    if (bid < 64) {
        // ---- out2 role ----
        const int b  = bid >> 2;
        const int c0 = ((bid >> 1) & 1) * 64;
        const int k0 = (bid & 1) * 64;
        const float* A = Y + (size_t)(b * 128 + c0) * ND;           // s0sig (unmasked)
        const float* W = Y + (size_t)(2048 + b * 128 + k0) * ND;    // s1sig (unmasked)
        const int ml = t >> 2;
        const int jl = (t & 3) * 4;
        const int ty = t >> 4;
        const int tx = t & 15;
        float acc[4][4] = {};
        for (int j0 = 0; j0 < 256; j0 += 16) {
            float4 a  = *(const float4*)(A + ml * ND + j0 + jl);
            float4 bb = *(const float4*)(W + ml * ND + j0 + jl);
            As[jl + 0][ml] = a.x;  As[jl + 1][ml] = a.y;  As[jl + 2][ml] = a.z;  As[jl + 3][ml] = a.w;
            Bs[jl + 0][ml] = bb.x; Bs[jl + 1][ml] = bb.y; Bs[jl + 2][ml] = bb.z; Bs[jl + 3][ml] = bb.w;
            __syncthreads();
#pragma unroll
            for (int jj = 0; jj < 16; ++jj) {
                float4 av = *(const float4*)&As[jj][ty * 4];
                float4 bv = *(const float4*)&Bs[jj][tx * 4];
                acc[0][0] += av.x * bv.x; acc[0][1] += av.x * bv.y; acc[0][2] += av.x * bv.z; acc[0][3] += av.x * bv.w;
                acc[1][0] += av.y * bv.x; acc[1][1] += av.y * bv.y; acc[1][2] += av.y * bv.z; acc[1][3] += av.y * bv.w;
                acc[2][0] += av.z * bv.x; acc[2][1] += av.z * bv.y; acc[2][2] += av.z * bv.z; acc[2][3] += av.z * bv.w;
                acc[3][0] += av.w * bv.x; acc[3][1] += av.w * bv.y; acc[3][2] += av.w * bv.z; acc[3][3] += av.w * bv.w;
            }
            __syncthreads();
        }
        const float scale = 1.f / 256.f;
#pragma unroll
        for (int i = 0; i < 4; ++i) {
            float4 o = make_float4(acc[i][0] * scale, acc[i][1] * scale, acc[i][2] * scale, acc[i][3] * scale);
            *(float4*)(out2 + ((size_t)(b * 128 + c0 + ty * 4 + i)) * 128 + k0 + tx * 4) = o;
        }
    } else if (bid < 320) {
        // ---- out0 role ---- (256 blocks, each handles 8 consecutive c rows for one b)
        const int local = bid - 64;
        const int b  = local >> 4;
        const int c0 = (local & 15) * 8;
        const float tv  = tvec[b * ND + t];
        const float inv = 1.f / (float)klen[b];
#pragma unroll
        for (int ci = 0; ci < 8; ++ci) {
            const int bc = b * 128 + c0 + ci;
            const float cm = (cmask[bc] != 0) ? 1.f : 0.f;
            const float s0 = Y[(size_t)bc * ND + t];
            out0[(size_t)bc * ND + t] = tanhf(cm * s0 * tv * inv);
        }
    } else {
        // ---- out1 stream role ---- one block per (b,c); f covers d via float4, g covers k phase
        const int bc = bid - 320;      // b*128 + c
        const int b  = bc >> 7;
        const int f  = t & 63;
        const int g  = t >> 6;
        float4 s0v = *(const float4*)(Y + (size_t)bc * ND + f * 4);
        const bool cm = cmask[bc] != 0;
        float4 v0 = cm ? s0v : make_float4(0.f, 0.f, 0.f, 0.f);

        const float* s1p = Y  + (size_t)(2048 + b * 128 + g) * ND + f * 4;
        const float* kcp = kc + (size_t)(b * 128 + g) * ND + f * 4;
        const int*   kmb = kmask + b * 128;
        float*       op  = out1 + (size_t)bc * 128 * ND + (size_t)g * ND + f * 4;

#pragma unroll 4
        for (int k0 = 0; k0 < 32; ++k0) {
            const int k = k0 * 4 + g;
            const float km = (float)kmb[k];
            float4 s1v = *(const float4*)s1p;
            float4 kcv = *(const float4*)kcp;
            float4 o = make_float4(v0.x * km * kcv.x * s1v.x,
                                   v0.y * km * kcv.y * s1v.y,
                                   v0.z * km * kcv.z * s1v.z,
                                   v0.w * km * kcv.w * s1v.w);
            *(float4*)op = o;
            s1p += 4 * ND; kcp += 4 * ND; op += 4 * ND;
        }
    }
}

extern "C" void kernel_launch(void* const* d_in, const int* in_sizes, int n_in,
                              void* d_out, int out_size, void* d_ws, size_t ws_size,
                              hipStream_t stream) {
    const float* q     = (const float*)d_in[0];
    const float* kc    = (const float*)d_in[1];
    const float* W0    = (const float*)d_in[2];
    const float* W1    = (const float*)d_in[3];
    const float* g0    = (const float*)d_in[4];
    const float* b0    = (const float*)d_in[5];
    const float* g1    = (const float*)d_in[6];
    const float* b1    = (const float*)d_in[7];
    const int*   cmask = (const int*)d_in[8];
    const int*   kmask = (const int*)d_in[9];
    const int*   klen  = (const int*)d_in[10];

    float* ws = (float*)d_ws;
    float* Y  = ws;                 // 4096*256 = 1048576 f32 (sigmoid(BN(.)) in place after k_sau)
    float* tv = ws + 1048576;       // 16*256 = 4096

    float* o    = (float*)d_out;
    float* out0 = o;                 // 16*128*256      = 524288
    float* out1 = o + 524288;        // 16*128*128*256  = 67108864
    float* out2 = o + 67633152;      // 16*128*128      = 262144

    k_gemm<<<dim3(64, 4), 256, 0, stream>>>(q, kc, W0, W1, Y, tv);
    k_sau <<<256,         256, 0, stream>>>(Y, kc, g0, b0, g1, b1, kmask, tv);
    k_tail<<<2368,        256, 0, stream>>>(Y, kc, cmask, kmask, klen, tv, out0, out1, out2);
}

// Round 3
// 320.101 us; speedup vs baseline: 1.0479x; 1.0135x over previous
//
#include <hip/hip_runtime.h>

// Problem: B=16, C=128, K=128, D=256. Inputs f32, outputs FLOAT32.
// d_out (float): out0 (B,C,D) @ 0, out1 (B,C,K,D) @ 524288, out2 (B,C,K) @ 67633152.

#define NB 16
#define NC 128
#define NK 128
#define ND 256

typedef float f4v __attribute__((ext_vector_type(4)));

// ---------------- Kernel 1: dual SGEMM  Y[m,d] = sum_j A[m,j]*W[d,j]  (+ zero tvec) --------
// M = 4096 (rows 0..2047 = q with W0, rows 2048..4095 = kc with W1), K=256, N=256.
__global__ __launch_bounds__(256) void k_gemm(const float* __restrict__ q,
                                              const float* __restrict__ kc,
                                              const float* __restrict__ W0,
                                              const float* __restrict__ W1,
                                              float* __restrict__ Y,
                                              float* __restrict__ tvec) {
    if (blockIdx.x == 0 && blockIdx.y == 0) {
        for (int i = threadIdx.x; i < NB * ND; i += 256) tvec[i] = 0.f;
    }
    __shared__ float As[16][64];
    __shared__ float Bs[16][64];
    const int m0 = blockIdx.x * 64;
    const int d0 = blockIdx.y * 64;
    const int t  = threadIdx.x;
    const float* A = (m0 < 2048) ? (q + (size_t)m0 * ND) : (kc + (size_t)(m0 - 2048) * ND);
    const float* W = (m0 < 2048) ? W0 : W1;
    const int ml = t >> 2;
    const int jl = (t & 3) * 4;
    const int ty = t >> 4;
    const int tx = t & 15;

    float acc[4][4] = {};
    for (int j0 = 0; j0 < 256; j0 += 16) {
        float4 a = *(const float4*)(A + ml * ND + j0 + jl);
        float4 b = *(const float4*)(W + (d0 + ml) * ND + j0 + jl);
        As[jl + 0][ml] = a.x; As[jl + 1][ml] = a.y; As[jl + 2][ml] = a.z; As[jl + 3][ml] = a.w;
        Bs[jl + 0][ml] = b.x; Bs[jl + 1][ml] = b.y; Bs[jl + 2][ml] = b.z; Bs[jl + 3][ml] = b.w;
        __syncthreads();
#pragma unroll
        for (int jj = 0; jj < 16; ++jj) {
            float4 av = *(const float4*)&As[jj][ty * 4];
            float4 bv = *(const float4*)&Bs[jj][tx * 4];
            acc[0][0] += av.x * bv.x; acc[0][1] += av.x * bv.y; acc[0][2] += av.x * bv.z; acc[0][3] += av.x * bv.w;
            acc[1][0] += av.y * bv.x; acc[1][1] += av.y * bv.y; acc[1][2] += av.y * bv.z; acc[1][3] += av.y * bv.w;
            acc[2][0] += av.z * bv.x; acc[2][1] += av.z * bv.y; acc[2][2] += av.z * bv.z; acc[2][3] += av.z * bv.w;
            acc[3][0] += av.w * bv.x; acc[3][1] += av.w * bv.y; acc[3][2] += av.w * bv.z; acc[3][3] += av.w * bv.w;
        }
        __syncthreads();
    }
#pragma unroll
    for (int i = 0; i < 4; ++i) {
        float4 o = make_float4(acc[i][0], acc[i][1], acc[i][2], acc[i][3]);
        *(float4*)(Y + (size_t)(m0 + ty * 4 + i) * ND + d0 + tx * 4) = o;
    }
}

// ---------------- Kernel 2: fused BN-stats + sigmoid-apply + u materialization --------------
// One block per channel (256: 0..127 bn0/s0 rows, 128..255 bn1/s1 rows). Thread t = column d.
__global__ __launch_bounds__(256) void k_sau(float* __restrict__ Y,
                                             const float* __restrict__ kc,
                                             const float* __restrict__ g0, const float* __restrict__ b0,
                                             const float* __restrict__ g1, const float* __restrict__ b1,
                                             const int* __restrict__ kmask,
                                             float* __restrict__ U,
                                             float* __restrict__ tvec) {
    const int ch = blockIdx.x;
    const int t  = threadIdx.x;
    const int rbase = (ch < 128) ? ch : (2048 + (ch - 128));
    float v[NB];
    float s = 0.f, s2 = 0.f;
#pragma unroll
    for (int b = 0; b < NB; ++b) {
        v[b] = Y[(size_t)(rbase + b * 128) * ND + t];
        s += v[b]; s2 += v[b] * v[b];
    }
#pragma unroll
    for (int off = 32; off > 0; off >>= 1) {
        s  += __shfl_down(s,  off, 64);
        s2 += __shfl_down(s2, off, 64);
    }
    __shared__ float r1[4], r2[4];
    __shared__ float bsc, bsh;
    const int w = t >> 6;
    if ((t & 63) == 0) { r1[w] = s; r2[w] = s2; }
    __syncthreads();
    if (t == 0) {
        s  = r1[0] + r1[1] + r1[2] + r1[3];
        s2 = r2[0] + r2[1] + r2[2] + r2[3];
        float mean = s * (1.f / 4096.f);
        float var  = s2 * (1.f / 4096.f) - mean * mean;   // biased, matches torch/jnp
        float rstd = rsqrtf(var + 1e-5f);
        float g  = (ch < 128) ? g0[ch] : g1[ch - 128];
        float be = (ch < 128) ? b0[ch] : b1[ch - 128];
        bsc = g * rstd;
        bsh = be - mean * g * rstd;
    }
    __syncthreads();
    const float sc = bsc, sh = bsh;
    if (ch < 128) {
#pragma unroll
        for (int b = 0; b < NB; ++b) {
            float sig = 1.f / (1.f + __expf(-(v[b] * sc + sh)));
            Y[(size_t)(rbase + b * 128) * ND + t] = sig;
        }
    } else {
        const int k = ch - 128;
#pragma unroll
        for (int b = 0; b < NB; ++b) {
            float sig = 1.f / (1.f + __expf(-(v[b] * sc + sh)));
            Y[(size_t)(rbase + b * 128) * ND + t] = sig;          // s1sig for out2 (unmasked)
            const int r = b * 128 + k;
            if (kmask[r] != 0) {                                   // wave-uniform
                float u = kc[(size_t)r * ND + t] * sig;
                U[(size_t)r * ND + t] = u;
                atomicAdd(&tvec[b * ND + t], u);
            } else {
                U[(size_t)r * ND + t] = 0.f;
            }
        }
    }
}

// ---------------- Kernel 3: fat tail — out2 GEMM + out0 + XCD-swizzled out1 stream ----------
// Blocks 0..63: out2 per-b 64x64 GEMM tiles (reads unmasked s0sig/s1sig from Y).
// Blocks 64..319: out0.
// Blocks 320..2367: out1[b,c,k,d] = (cmask*s0sig)[d] * U[b,k,d]; b chosen so that
//                   XCD x (= bid%8) only ever touches b in {2x, 2x+1} -> hot 512KB read set.
__global__ __launch_bounds__(256) void k_tail(const float* __restrict__ Y,
                                              const float* __restrict__ U,
                                              const int* __restrict__ cmask,
                                              const int* __restrict__ klen,
                                              const float* __restrict__ tvec,
                                              float* __restrict__ out0,
                                              float* __restrict__ out1,
                                              float* __restrict__ out2) {
    __shared__ float As[16][64];
    __shared__ float Bs[16][64];
    const int bid = blockIdx.x;
    const int t   = threadIdx.x;

    if (bid < 64) {
        // ---- out2 role ----
        const int b  = bid >> 2;
        const int c0 = ((bid >> 1) & 1) * 64;
        const int k0 = (bid & 1) * 64;
        const float* A = Y + (size_t)(b * 128 + c0) * ND;           // s0sig (unmasked)
        const float* W = Y + (size_t)(2048 + b * 128 + k0) * ND;    // s1sig (unmasked)
        const int ml = t >> 2;
        const int jl = (t & 3) * 4;
        const int ty = t >> 4;
        const int tx = t & 15;
        float acc[4][4] = {};
        for (int j0 = 0; j0 < 256; j0 += 16) {
            float4 a  = *(const float4*)(A + ml * ND + j0 + jl);
            float4 bb = *(const float4*)(W + ml * ND + j0 + jl);
            As[jl + 0][ml] = a.x;  As[jl + 1][ml] = a.y;  As[jl + 2][ml] = a.z;  As[jl + 3][ml] = a.w;
            Bs[jl + 0][ml] = bb.x; Bs[jl + 1][ml] = bb.y; Bs[jl + 2][ml] = bb.z; Bs[jl + 3][ml] = bb.w;
            __syncthreads();
#pragma unroll
            for (int jj = 0; jj < 16; ++jj) {
                float4 av = *(const float4*)&As[jj][ty * 4];
                float4 bv = *(const float4*)&Bs[jj][tx * 4];
                acc[0][0] += av.x * bv.x; acc[0][1] += av.x * bv.y; acc[0][2] += av.x * bv.z; acc[0][3] += av.x * bv.w;
                acc[1][0] += av.y * bv.x; acc[1][1] += av.y * bv.y; acc[1][2] += av.y * bv.z; acc[1][3] += av.y * bv.w;
                acc[2][0] += av.z * bv.x; acc[2][1] += av.z * bv.y; acc[2][2] += av.z * bv.z; acc[2][3] += av.z * bv.w;
                acc[3][0] += av.w * bv.x; acc[3][1] += av.w * bv.y; acc[3][2] += av.w * bv.z; acc[3][3] += av.w * bv.w;
            }
            __syncthreads();
        }
        const float scale = 1.f / 256.f;
#pragma unroll
        for (int i = 0; i < 4; ++i) {
            float4 o = make_float4(acc[i][0] * scale, acc[i][1] * scale, acc[i][2] * scale, acc[i][3] * scale);
            *(float4*)(out2 + ((size_t)(b * 128 + c0 + ty * 4 + i)) * 128 + k0 + tx * 4) = o;
        }
    } else if (bid < 320) {
        // ---- out0 role ---- (256 blocks, 8 consecutive c rows each)
        const int local = bid - 64;
        const int b  = local >> 4;
        const int c0 = (local & 15) * 8;
        const float tv  = tvec[b * ND + t];
        const float inv = 1.f / (float)klen[b];
#pragma unroll
        for (int ci = 0; ci < 8; ++ci) {
            const int bc = b * 128 + c0 + ci;
            const float cm = (cmask[bc] != 0) ? 1.f : 0.f;
            const float s0 = Y[(size_t)bc * ND + t];
            out0[(size_t)bc * ND + t] = tanhf(cm * s0 * tv * inv);
        }
    } else {
        // ---- out1 stream role, XCD-pinned b ----
        const int s   = bid - 320;          // 0..2047; bid%8 == s%8 (320 % 8 == 0)
        const int xcd = s & 7;
        const int j   = s >> 3;             // 0..255
        const int b   = (xcd << 1) | (j >> 7);
        const int c   = j & 127;
        const int bc  = b * 128 + c;
        const int f   = t & 63;
        const int g   = t >> 6;

        float4 s0v = *(const float4*)(Y + (size_t)bc * ND + f * 4);
        const bool cm = cmask[bc] != 0;
        float4 v0 = cm ? s0v : make_float4(0.f, 0.f, 0.f, 0.f);

        const float* up = U    + (size_t)(b * 128 + g) * ND + f * 4;
        float*       op = out1 + (size_t)bc * 128 * ND + (size_t)g * ND + f * 4;

#pragma unroll 8
        for (int k0 = 0; k0 < 32; ++k0) {
            float4 uv = *(const float4*)up;
            float4 o = make_float4(v0.x * uv.x, v0.y * uv.y, v0.z * uv.z, v0.w * uv.w);
            __builtin_nontemporal_store(*(const f4v*)&o, (f4v*)op);
            up += 4 * ND;
            op += 4 * ND;
        }

        if (g == 0 && false) { /* out0 handled by its own role */ }
    }
}

extern "C" void kernel_launch(void* const* d_in, const int* in_sizes, int n_in,
                              void* d_out, int out_size, void* d_ws, size_t ws_size,
                              hipStream_t stream) {
    const float* q     = (const float*)d_in[0];
    const float* kc    = (const float*)d_in[1];
    const float* W0    = (const float*)d_in[2];
    const float* W1    = (const float*)d_in[3];
    const float* g0    = (const float*)d_in[4];
    const float* b0    = (const float*)d_in[5];
    const float* g1    = (const float*)d_in[6];
    const float* b1    = (const float*)d_in[7];
    const int*   cmask = (const int*)d_in[8];
    const int*   kmask = (const int*)d_in[9];
    const int*   klen  = (const int*)d_in[10];

    float* ws = (float*)d_ws;
    float* Y  = ws;                 // 4096*256 = 1048576 f32 (sigmoids in place after k_sau)
    float* tv = ws + 1048576;       // 16*256 = 4096
    float* U  = ws + 1052672;       // 2048*256 = 524288  (u = kmask*kc*s1sig)

    float* o    = (float*)d_out;
    float* out0 = o;                 // 16*128*256      = 524288
    float* out1 = o + 524288;        // 16*128*128*256  = 67108864
    float* out2 = o + 67633152;      // 16*128*128      = 262144

    k_gemm<<<dim3(64, 4), 256, 0, stream>>>(q, kc, W0, W1, Y, tv);
    k_sau <<<256,         256, 0, stream>>>(Y, kc, g0, b0, g1, b1, kmask, U, tv);
    k_tail<<<2368,        256, 0, stream>>>(Y, U, cmask, klen, tv, out0, out1, out2);
}